// Round 1
// baseline (3151.302 us; speedup 1.0000x reference)
//
#include <hip/hip_runtime.h>

#define TPB 256
#define HWSZ 9216      // 96*96
#define NPIX 73728     // 8*96*96

__device__ __forceinline__ float sigf(float v) { return 1.0f / (1.0f + __expf(-v)); }

// ---------------- pack weight matrices to K-major ----------------
// Gt[256][1024]: Gt[k][d*256+dd] = g_d[dd][k]   (gate logit j = sum_k y[k]*Gt[k][j])
// Ft[256][256]:  Ft[k][j] = fuse_w[j][k]
// W1t[256][1024]: W1t[k][j] = ff1_w[j][k]
// W2t[512][256]:  W2t[k][j] = ff2_w[j][k]
__global__ __launch_bounds__(TPB) void k_pack(
    const float* __restrict__ lrg, const float* __restrict__ rlg,
    const float* __restrict__ tbg, const float* __restrict__ btg,
    const float* __restrict__ fusew, const float* __restrict__ ff1w,
    const float* __restrict__ ff2w,
    float* __restrict__ Gt, float* __restrict__ Ft,
    float* __restrict__ W1t, float* __restrict__ W2t) {
  int i = blockIdx.x * TPB + threadIdx.x;
  if (i < 262144) {
    int k = i >> 10, j = i & 1023;
    int d = j >> 8, dd = j & 255;
    const float* g = (d == 0) ? lrg : (d == 1) ? rlg : (d == 2) ? tbg : btg;
    Gt[i] = g[dd * 256 + k];
  } else if (i < 327680) {
    int t = i - 262144;
    int k = t >> 8, j = t & 255;
    Ft[t] = fusew[j * 256 + k];
  } else if (i < 589824) {
    int t = i - 327680;
    int k = t >> 10, j = t & 1023;
    W1t[t] = ff1w[j * 256 + k];
  } else if (i < 720896) {
    int t = i - 589824;
    int k = t >> 8, j = t & 255;
    W2t[t] = ff2w[j * 512 + k];
  }
}

// ---------------- per-(n,c) LayerNorm2d stats over H*W ----------------
__global__ __launch_bounds__(TPB) void k_stats(const float* __restrict__ src,
                                               float* __restrict__ mean,
                                               float* __restrict__ rstd) {
  int nc = blockIdx.x;
  const float* p = src + nc * HWSZ;
  float s = 0.f, s2 = 0.f;
  for (int i = threadIdx.x; i < HWSZ; i += TPB) {
    float v = p[i];
    s += v;
    s2 = fmaf(v, v, s2);
  }
#pragma unroll
  for (int off = 32; off > 0; off >>= 1) {
    s += __shfl_down(s, off);
    s2 += __shfl_down(s2, off);
  }
  __shared__ float ls[4], ls2[4];
  int lane = threadIdx.x & 63, wv = threadIdx.x >> 6;
  if (lane == 0) { ls[wv] = s; ls2[wv] = s2; }
  __syncthreads();
  if (threadIdx.x == 0) {
    float S = ls[0] + ls[1] + ls[2] + ls[3];
    float S2 = ls2[0] + ls2[1] + ls2[2] + ls2[3];
    float m = S * (1.0f / HWSZ);
    float var = S2 * (1.0f / HWSZ) - m * m;
    mean[nc] = m;
    rstd[nc] = rsqrtf(fmaxf(var, 0.f) + 1e-6f);
  }
}

// ---------------- ln1 + depthwise 3x3 -> y (NHWC) ----------------
// block: (n, h, cblk of 32). LDS holds 3 ln1-applied rows x 32 ch (w-halo padded).
__global__ __launch_bounds__(TPB) void k_lndw(
    const float* __restrict__ x, const float* __restrict__ mean1,
    const float* __restrict__ rstd1, const float* __restrict__ ln1w,
    const float* __restrict__ ln1b, const float* __restrict__ dww,
    const float* __restrict__ dwb, float* __restrict__ y) {
  __shared__ float xl[3][32][101];  // [row][c][w+1], 101 stride -> conflict-free c-strided reads
  int tid = threadIdx.x;
  int bid = blockIdx.x;
  int cb = (bid & 7) * 32;
  int h = (bid >> 3) % 96;
  int n = bid / 768;

  if (tid < 192) {  // zero w-halo columns
    int col = (tid & 1) ? 97 : 0;
    int rc = tid >> 1;
    xl[rc >> 5][rc & 31][col] = 0.f;
  }
  for (int i = tid; i < 3 * 32 * 96; i += TPB) {
    int w = i % 96;
    int rc = i / 96;
    int cc = rc & 31, rr = rc >> 5;
    int hh = h + rr - 1;
    float v = 0.f;
    if (hh >= 0 && hh < 96) {
      int c = cb + cc;
      int nc = n * 256 + c;
      float xv = x[nc * HWSZ + hh * 96 + w];
      v = (xv - mean1[nc]) * rstd1[nc] * ln1w[c] + ln1b[c];
    }
    xl[rr][cc][w + 1] = v;
  }
  __syncthreads();

  int cc = tid & 31, wg = tid >> 5;
  int c = cb + cc;
  float wgt[9];
#pragma unroll
  for (int t = 0; t < 9; ++t) wgt[t] = dww[t * 256 + c];
  float bias = dwb[c];
  for (int wi = 0; wi < 12; ++wi) {
    int w = wg * 12 + wi;
    float acc = bias;
#pragma unroll
    for (int kh = 0; kh < 3; ++kh)
#pragma unroll
      for (int kw = 0; kw < 3; ++kw)
        acc = fmaf(xl[kh][cc][w + kw], wgt[kh * 3 + kw], acc);
    y[((n * 96 + h) * 96 + w) * 256 + c] = acc;
  }
}

// ---------------- scan pair: gate GEMM + dwconv1d + sigmoid ----------------
// VERT=0: lr/rl along w (writes o).  VERT=1: tb/bt along h (o +=).
// Block: 16-pixel segment of one line. Gate GEMM (16x256)@(256x512).
template <int VERT>
__global__ __launch_bounds__(TPB) void k_scan(
    const float* __restrict__ y, const float* __restrict__ Gt,
    const float* __restrict__ dwaw, const float* __restrict__ dwab,
    const float* __restrict__ gab, const float* __restrict__ dwbw,
    const float* __restrict__ dwbb, const float* __restrict__ gbb_,
    float* __restrict__ o) {
  __shared__ float ylds[20][256];   // seg-2 .. seg+17
  __shared__ float glds[16][512];
  __shared__ float olds[16][256];
  int tid = threadIdx.x;
  int bid = blockIdx.x;
  int seg = bid % 6;
  int line = (bid / 6) % 96;
  int n = bid / 576;
  int p0 = seg * 16;

  for (int i = tid; i < 20 * 256; i += TPB) {
    int r = i >> 8, c = i & 255;
    int q = p0 - 2 + r;
    float v = 0.f;
    if (q >= 0 && q < 96) {
      int pix = VERT ? ((n * 96 + q) * 96 + line) : ((n * 96 + line) * 96 + q);
      v = y[pix * 256 + c];
    }
    ylds[r][c] = v;
  }

  int pt = tid >> 6;   // 0..3 -> pixels pt*4..+3
  int jt = tid & 63;   // j = jt*8..+7  (j<256: first dir, j>=256: second dir)
  float acc[4][8];
#pragma unroll
  for (int ii = 0; ii < 4; ++ii)
#pragma unroll
    for (int jj = 0; jj < 8; ++jj) acc[ii][jj] = 0.f;

  const float* gcol = Gt + (VERT ? 512 : 0);
  for (int kc = 0; kc < 256; kc += 16) {
    __syncthreads();
    for (int i = tid; i < 16 * 512; i += TPB) {
      int kk = i >> 9, j = i & 511;
      glds[kk][j] = gcol[(kc + kk) * 1024 + j];
    }
    __syncthreads();
#pragma unroll
    for (int kk = 0; kk < 16; ++kk) {
      float av[4];
#pragma unroll
      for (int ii = 0; ii < 4; ++ii) av[ii] = ylds[pt * 4 + ii + 2][kc + kk];
      const float4* g4 = reinterpret_cast<const float4*>(&glds[kk][jt * 8]);
      float4 b0 = g4[0], b1 = g4[1];
      float bv[8] = {b0.x, b0.y, b0.z, b0.w, b1.x, b1.y, b1.z, b1.w};
#pragma unroll
      for (int ii = 0; ii < 4; ++ii)
#pragma unroll
        for (int jj = 0; jj < 8; ++jj)
          acc[ii][jj] = fmaf(av[ii], bv[jj], acc[ii][jj]);
    }
  }
  __syncthreads();

  // epilogue: conv (second dir = reversed kernel) * sigmoid(gate)
  bool second = (jt >= 32);
  int cbase = (jt & 31) * 8;
  const float* dwv = second ? dwbw : dwaw;
  const float* dbv = second ? dwbb : dwab;
  const float* gbv = second ? gbb_ : gab;

  float part[4][8];
#pragma unroll
  for (int jj = 0; jj < 8; ++jj) {
    int c = cbase + jj;
    float w_[5];
#pragma unroll
    for (int t = 0; t < 5; ++t) w_[t] = dwv[t * 256 + c];
    if (second) {  // flipped scan == reversed kernel
      float ts = w_[0]; w_[0] = w_[4]; w_[4] = ts;
      ts = w_[1]; w_[1] = w_[3]; w_[3] = ts;
    }
    float cb = dbv[c];
    float gb = gbv[c];
#pragma unroll
    for (int ii = 0; ii < 4; ++ii) {
      int p = pt * 4 + ii;
      float conv = cb;
#pragma unroll
      for (int t = 0; t < 5; ++t) conv = fmaf(ylds[p + t][c], w_[t], conv);
      part[ii][jj] = conv * sigf(acc[ii][jj] + gb);
    }
  }

  if (!second) {
#pragma unroll
    for (int ii = 0; ii < 4; ++ii)
#pragma unroll
      for (int jj = 0; jj < 8; ++jj)
        olds[pt * 4 + ii][cbase + jj] = part[ii][jj];
  }
  __syncthreads();
  if (second) {
#pragma unroll
    for (int ii = 0; ii < 4; ++ii)
#pragma unroll
      for (int jj = 0; jj < 8; ++jj)
        olds[pt * 4 + ii][cbase + jj] += part[ii][jj];
  }
  __syncthreads();

  for (int i = tid; i < 16 * 256; i += TPB) {
    int p = i >> 8, c = i & 255;
    int pix = VERT ? ((n * 96 + p0 + p) * 96 + line) : ((n * 96 + line) * 96 + p0 + p);
    if (VERT)
      o[pix * 256 + c] += olds[p][c];
    else
      o[pix * 256 + c] = olds[p][c];
  }
}

// ---------------- fuse GEMM + residual: out(NCHW) = x + o @ Ft + fuse_b ----------------
__global__ __launch_bounds__(TPB) void k_fuse(
    const float* __restrict__ o, const float* __restrict__ Ft,
    const float* __restrict__ fuseb, const float* __restrict__ x,
    float* __restrict__ out) {
  __shared__ float alds[32][256];
  __shared__ float blds[16][256];
  __shared__ float olds[32][256];
  int tid = threadIdx.x;
  int pix0 = blockIdx.x * 32;
  int n = pix0 / HWSZ;
  int hw0 = pix0 % HWSZ;

  for (int i = tid; i < 32 * 256; i += TPB) {
    int p = i >> 8, c = i & 255;
    alds[p][c] = o[(pix0 + p) * 256 + c];
  }

  int pt = tid >> 5;  // 0..7 -> pixels pt*4..+3
  int jt = tid & 31;  // j = jt*8..+7
  float acc[4][8];
#pragma unroll
  for (int ii = 0; ii < 4; ++ii)
#pragma unroll
    for (int jj = 0; jj < 8; ++jj) acc[ii][jj] = 0.f;

  for (int kc = 0; kc < 256; kc += 16) {
    __syncthreads();
    for (int i = tid; i < 16 * 256; i += TPB) {
      int kk = i >> 8, j = i & 255;
      blds[kk][j] = Ft[(kc + kk) * 256 + j];
    }
    __syncthreads();
#pragma unroll
    for (int kk = 0; kk < 16; ++kk) {
      float av[4];
#pragma unroll
      for (int ii = 0; ii < 4; ++ii) av[ii] = alds[pt * 4 + ii][kc + kk];
      const float4* b4 = reinterpret_cast<const float4*>(&blds[kk][jt * 8]);
      float4 b0 = b4[0], b1 = b4[1];
      float bv[8] = {b0.x, b0.y, b0.z, b0.w, b1.x, b1.y, b1.z, b1.w};
#pragma unroll
      for (int ii = 0; ii < 4; ++ii)
#pragma unroll
        for (int jj = 0; jj < 8; ++jj)
          acc[ii][jj] = fmaf(av[ii], bv[jj], acc[ii][jj]);
    }
  }
  __syncthreads();
#pragma unroll
  for (int ii = 0; ii < 4; ++ii)
#pragma unroll
    for (int jj = 0; jj < 8; ++jj)
      olds[pt * 4 + ii][jt * 8 + jj] = acc[ii][jj] + fuseb[jt * 8 + jj];
  __syncthreads();
  for (int i = tid; i < 8192; i += TPB) {
    int c = i >> 5, p = i & 31;                 // coalesced NCHW
    int addr = (n * 256 + c) * HWSZ + hw0 + p;
    out[addr] = x[addr] + olds[p][c];
  }
}

// ---------------- ln2 + ff1 + GLU + ff2 + residual (out +=) ----------------
__global__ __launch_bounds__(TPB) void k_ff(
    const float* __restrict__ xres, const float* __restrict__ mean2,
    const float* __restrict__ rstd2, const float* __restrict__ ln2w,
    const float* __restrict__ ln2b, const float* __restrict__ W1t,
    const float* __restrict__ ff1b, const float* __restrict__ W2t,
    const float* __restrict__ ff2b, float* __restrict__ out) {
  __shared__ float hlds[32][256];
  __shared__ float wlds[16][256];
  __shared__ float tlds[32][256];
  int tid = threadIdx.x;
  int pix0 = blockIdx.x * 32;
  int n = pix0 / HWSZ;
  int hw0 = pix0 % HWSZ;

  for (int i = tid; i < 8192; i += TPB) {
    int c = i >> 5, p = i & 31;                 // coalesced NCHW read
    int nc = n * 256 + c;
    float v = xres[nc * HWSZ + hw0 + p];
    hlds[p][c] = (v - mean2[nc]) * rstd2[nc] * ln2w[c] + ln2b[c];
  }

  int pt = tid >> 5, jt = tid & 31;
  float zacc[4][8];
#pragma unroll
  for (int ii = 0; ii < 4; ++ii)
#pragma unroll
    for (int jj = 0; jj < 8; ++jj) zacc[ii][jj] = 0.f;

  for (int jc = 0; jc < 4; ++jc) {  // 4 chunks of 128 GLU pairs
    float tacc[4][8];
#pragma unroll
    for (int ii = 0; ii < 4; ++ii)
#pragma unroll
      for (int jj = 0; jj < 8; ++jj) tacc[ii][jj] = 0.f;

    // GEMM1: t1 chunk = h @ W1t[:, a-cols jc*128.. | g-cols 512+jc*128..]
    for (int kc = 0; kc < 256; kc += 16) {
      __syncthreads();
      for (int i = tid; i < 4096; i += TPB) {
        int kk = i >> 8, j = i & 255;
        int col = (j < 128) ? (jc * 128 + j) : (512 + jc * 128 + (j - 128));
        wlds[kk][j] = W1t[(kc + kk) * 1024 + col];
      }
      __syncthreads();
#pragma unroll
      for (int kk = 0; kk < 16; ++kk) {
        float av[4];
#pragma unroll
        for (int ii = 0; ii < 4; ++ii) av[ii] = hlds[pt * 4 + ii][kc + kk];
        const float4* b4 = reinterpret_cast<const float4*>(&wlds[kk][jt * 8]);
        float4 b0 = b4[0], b1 = b4[1];
        float bv[8] = {b0.x, b0.y, b0.z, b0.w, b1.x, b1.y, b1.z, b1.w};
#pragma unroll
        for (int ii = 0; ii < 4; ++ii)
#pragma unroll
          for (int jj = 0; jj < 8; ++jj)
            tacc[ii][jj] = fmaf(av[ii], bv[jj], tacc[ii][jj]);
      }
    }
    __syncthreads();
#pragma unroll
    for (int ii = 0; ii < 4; ++ii)
#pragma unroll
      for (int jj = 0; jj < 8; ++jj) {
        int col = jt * 8 + jj;
        float bias = (col < 128) ? ff1b[jc * 128 + col]
                                 : ff1b[512 + jc * 128 + (col - 128)];
        tlds[pt * 4 + ii][col] = tacc[ii][jj] + bias;
      }
    __syncthreads();
    // GLU in place: u[j] = a[j]*sig(g[j])
    for (int i = tid; i < 32 * 128; i += TPB) {
      int p = i >> 7, j = i & 127;
      tlds[p][j] = tlds[p][j] * sigf(tlds[p][j + 128]);
    }
    // GEMM2 partial: zacc += u @ W2t[jc*128 .. jc*128+127, :]
    for (int kc2 = 0; kc2 < 128; kc2 += 16) {
      __syncthreads();
      for (int i = tid; i < 4096; i += TPB) {
        int kk = i >> 8, j = i & 255;
        wlds[kk][j] = W2t[(jc * 128 + kc2 + kk) * 256 + j];
      }
      __syncthreads();
#pragma unroll
      for (int kk = 0; kk < 16; ++kk) {
        float av[4];
#pragma unroll
        for (int ii = 0; ii < 4; ++ii) av[ii] = tlds[pt * 4 + ii][kc2 + kk];
        const float4* b4 = reinterpret_cast<const float4*>(&wlds[kk][jt * 8]);
        float4 b0 = b4[0], b1 = b4[1];
        float bv[8] = {b0.x, b0.y, b0.z, b0.w, b1.x, b1.y, b1.z, b1.w};
#pragma unroll
        for (int ii = 0; ii < 4; ++ii)
#pragma unroll
          for (int jj = 0; jj < 8; ++jj)
            zacc[ii][jj] = fmaf(av[ii], bv[jj], zacc[ii][jj]);
      }
    }
  }
  __syncthreads();
#pragma unroll
  for (int ii = 0; ii < 4; ++ii)
#pragma unroll
    for (int jj = 0; jj < 8; ++jj)
      tlds[pt * 4 + ii][jt * 8 + jj] = zacc[ii][jj] + ff2b[jt * 8 + jj];
  __syncthreads();
  for (int i = tid; i < 8192; i += TPB) {
    int c = i >> 5, p = i & 31;
    int addr = (n * 256 + c) * HWSZ + hw0 + p;
    out[addr] += tlds[p][c];
  }
}

extern "C" void kernel_launch(void* const* d_in, const int* in_sizes, int n_in,
                              void* d_out, int out_size, void* d_ws, size_t ws_size,
                              hipStream_t stream) {
  (void)in_sizes; (void)n_in; (void)out_size; (void)ws_size;
  const float* x     = (const float*)d_in[0];
  const float* ln1w  = (const float*)d_in[1];
  const float* ln1b  = (const float*)d_in[2];
  const float* dww   = (const float*)d_in[3];
  const float* dwb   = (const float*)d_in[4];
  const float* lr_w  = (const float*)d_in[5];
  const float* lr_b  = (const float*)d_in[6];
  const float* lr_gw = (const float*)d_in[7];
  const float* lr_gb = (const float*)d_in[8];
  const float* rl_w  = (const float*)d_in[9];
  const float* rl_b  = (const float*)d_in[10];
  const float* rl_gw = (const float*)d_in[11];
  const float* rl_gb = (const float*)d_in[12];
  const float* tb_w  = (const float*)d_in[13];
  const float* tb_b  = (const float*)d_in[14];
  const float* tb_gw = (const float*)d_in[15];
  const float* tb_gb = (const float*)d_in[16];
  const float* bt_w  = (const float*)d_in[17];
  const float* bt_b  = (const float*)d_in[18];
  const float* bt_gw = (const float*)d_in[19];
  const float* bt_gb = (const float*)d_in[20];
  const float* fusew = (const float*)d_in[21];
  const float* fuseb = (const float*)d_in[22];
  const float* ln2w  = (const float*)d_in[23];
  const float* ln2b  = (const float*)d_in[24];
  const float* ff1w  = (const float*)d_in[25];
  const float* ff1b  = (const float*)d_in[26];
  const float* ff2w  = (const float*)d_in[27];
  const float* ff2b  = (const float*)d_in[28];

  float* out = (float*)d_out;
  float* ws  = (float*)d_ws;
  float* y     = ws;                    // 18874368 floats (NHWC)
  float* o     = ws + 18874368;         // 18874368 floats (NHWC)
  float* mean1 = ws + 2 * 18874368;
  float* rstd1 = mean1 + 2048;
  float* mean2 = rstd1 + 2048;
  float* rstd2 = mean2 + 2048;
  float* Gt    = rstd2 + 2048;          // 256*1024
  float* Ft    = Gt + 262144;           // 256*256
  float* W1t   = Ft + 65536;            // 256*1024
  float* W2t   = W1t + 262144;          // 512*256

  k_pack<<<2816, TPB, 0, stream>>>(lr_gw, rl_gw, tb_gw, bt_gw, fusew, ff1w, ff2w,
                                   Gt, Ft, W1t, W2t);
  k_stats<<<2048, TPB, 0, stream>>>(x, mean1, rstd1);
  k_lndw<<<6144, TPB, 0, stream>>>(x, mean1, rstd1, ln1w, ln1b, dww, dwb, y);
  k_scan<0><<<4608, TPB, 0, stream>>>(y, Gt, lr_w, lr_b, lr_gb, rl_w, rl_b, rl_gb, o);
  k_scan<1><<<4608, TPB, 0, stream>>>(y, Gt, tb_w, tb_b, tb_gb, bt_w, bt_b, bt_gb, o);
  k_fuse<<<2304, TPB, 0, stream>>>(o, Ft, fuseb, x, out);
  k_stats<<<2048, TPB, 0, stream>>>(out, mean2, rstd2);
  k_ff<<<2304, TPB, 0, stream>>>(out, mean2, rstd2, ln2w, ln2b, W1t, ff1b,
                                 W2t, ff2b, out);
}

// Round 2
// 836.406 us; speedup vs baseline: 3.7677x; 3.7677x over previous
//
#include <hip/hip_runtime.h>

#define TPB 256
#define HWSZ 9216      // 96*96

typedef __attribute__((ext_vector_type(8))) short short8x;
typedef __attribute__((ext_vector_type(4))) float f32x4;
typedef unsigned short ushort_t;
typedef unsigned int uint_t;

__device__ __forceinline__ float sigf(float v) { return 1.0f / (1.0f + __expf(-v)); }

__device__ __forceinline__ ushort_t f2bf(float f) {
  uint_t u = __float_as_uint(f);
  u = (u + 0x7fffu + ((u >> 16) & 1u)) >> 16;
  return (ushort_t)u;
}
__device__ __forceinline__ float bf2f(ushort_t h) {
  return __uint_as_float(((uint_t)h) << 16);
}

// fp32 epilogue-LDS swizzle: bijective, 32 distinct banks across p=0..31 at fixed c
__device__ __forceinline__ int swz32(int p, int c) {
  return p * 1024 + (((c * 4) ^ ((p & 7) << 4)) ^ (((p >> 3) & 3) << 2));
}

// ---------------- pack weights to fragment-major bf16 ----------------
// tile(kt,nt): elem (l,j) = B[kt*32 + (l>>4)*8 + j][nt*16 + (l&15)]
// Gp: 4 dirs x [kt8][nt16][64][8]; Ftp: [8][16][64][8];
// W1p: [kt8][ntG64][64][8] with GLU-pair column permutation; W2p: [kt16][nt16][64][8]
__global__ __launch_bounds__(TPB) void k_pack(
    const float* __restrict__ lrg, const float* __restrict__ rlg,
    const float* __restrict__ tbg, const float* __restrict__ btg,
    const float* __restrict__ fusew, const float* __restrict__ ff1w,
    const float* __restrict__ ff2w,
    ushort_t* __restrict__ Gp, ushort_t* __restrict__ Ftp,
    ushort_t* __restrict__ W1p, ushort_t* __restrict__ W2p) {
  int i = blockIdx.x * TPB + threadIdx.x;
  if (i < 262144) {
    int d = i >> 16, r = i & 65535;
    int nt = (r >> 9) & 15, l = (r >> 3) & 63, j = r & 7;
    int kt = r >> 13;
    int k = kt * 32 + (l >> 4) * 8 + j;
    int n_ = nt * 16 + (l & 15);
    const float* g = (d == 0) ? lrg : (d == 1) ? rlg : (d == 2) ? tbg : btg;
    Gp[i] = f2bf(g[n_ * 256 + k]);
  } else if (i < 327680) {
    int r = i - 262144;
    int kt = r >> 13, nt = (r >> 9) & 15, l = (r >> 3) & 63, j = r & 7;
    int k = kt * 32 + (l >> 4) * 8 + j;
    int n_ = nt * 16 + (l & 15);
    Ftp[r] = f2bf(fusew[n_ * 256 + k]);
  } else if (i < 589824) {
    int r = i - 327680;
    int kt = r >> 15, ntG = (r >> 9) & 63, l = (r >> 3) & 63, j = r & 7;
    int k = kt * 32 + (l >> 4) * 8 + j;
    int P = ntG * 16 + (l & 15);
    int jc = P >> 8, pos = P & 255, sub = pos >> 6, off = pos & 63;
    int col = ((sub & 1) == 0) ? (jc * 128 + (sub >> 1) * 64 + off)
                               : (512 + jc * 128 + (sub >> 1) * 64 + off);
    W1p[r] = f2bf(ff1w[col * 256 + k]);
  } else if (i < 720896) {
    int r = i - 589824;
    int kt = r >> 13, nt = (r >> 9) & 15, l = (r >> 3) & 63, j = r & 7;
    int k = kt * 32 + (l >> 4) * 8 + j;
    int n_ = nt * 16 + (l & 15);
    W2p[r] = f2bf(ff2w[n_ * 512 + k]);
  }
}

// ---------------- per-(n,c) LayerNorm2d stats ----------------
__global__ __launch_bounds__(TPB) void k_stats(const float* __restrict__ src,
                                               float* __restrict__ mean,
                                               float* __restrict__ rstd) {
  int nc = blockIdx.x;
  const float* p = src + (long)nc * HWSZ;
  float s = 0.f, s2 = 0.f;
  for (int i = threadIdx.x; i < HWSZ; i += TPB) {
    float v = p[i];
    s += v;
    s2 = fmaf(v, v, s2);
  }
#pragma unroll
  for (int off = 32; off > 0; off >>= 1) {
    s += __shfl_down(s, off);
    s2 += __shfl_down(s2, off);
  }
  __shared__ float ls[4], ls2[4];
  int lane = threadIdx.x & 63, wv = threadIdx.x >> 6;
  if (lane == 0) { ls[wv] = s; ls2[wv] = s2; }
  __syncthreads();
  if (threadIdx.x == 0) {
    float S = ls[0] + ls[1] + ls[2] + ls[3];
    float S2 = ls2[0] + ls2[1] + ls2[2] + ls2[3];
    float m = S * (1.0f / HWSZ);
    float var = S2 * (1.0f / HWSZ) - m * m;
    mean[nc] = m;
    rstd[nc] = rsqrtf(fmaxf(var, 0.f) + 1e-6f);
  }
}

// ---------------- ln1 + depthwise 3x3 -> y (NHWC bf16) ----------------
__global__ __launch_bounds__(TPB) void k_lndw(
    const float* __restrict__ x, const float* __restrict__ mean1,
    const float* __restrict__ rstd1, const float* __restrict__ ln1w,
    const float* __restrict__ ln1b, const float* __restrict__ dww,
    const float* __restrict__ dwb, ushort_t* __restrict__ y) {
  __shared__ float xl[3][32][101];
  int tid = threadIdx.x;
  int bid = blockIdx.x;
  int cb = (bid & 7) * 32;
  int h = (bid >> 3) % 96;
  int n = bid / 768;

  if (tid < 192) {
    int col = (tid & 1) ? 97 : 0;
    int rc = tid >> 1;
    xl[rc >> 5][rc & 31][col] = 0.f;
  }
  for (int i = tid; i < 3 * 32 * 96; i += TPB) {
    int w = i % 96;
    int rc = i / 96;
    int cc = rc & 31, rr = rc >> 5;
    int hh = h + rr - 1;
    float v = 0.f;
    if (hh >= 0 && hh < 96) {
      int c = cb + cc;
      int nc = n * 256 + c;
      float xv = x[(long)nc * HWSZ + hh * 96 + w];
      v = (xv - mean1[nc]) * rstd1[nc] * ln1w[c] + ln1b[c];
    }
    xl[rr][cc][w + 1] = v;
  }
  __syncthreads();

  int cc = tid & 31, wg = tid >> 5;
  int c = cb + cc;
  float wgt[9];
#pragma unroll
  for (int t = 0; t < 9; ++t) wgt[t] = dww[t * 256 + c];
  float bias = dwb[c];
  for (int wi = 0; wi < 12; ++wi) {
    int w = wg * 12 + wi;
    float acc = bias;
#pragma unroll
    for (int kh = 0; kh < 3; ++kh)
#pragma unroll
      for (int kw = 0; kw < 3; ++kw)
        acc = fmaf(xl[kh][cc][w + kw], wgt[kh * 3 + kw], acc);
    y[((long)(n * 96 + h) * 96 + w) * 256 + c] = f2bf(acc);
  }
}

// ---------------- scan pair (MFMA): gate GEMM + dwconv1d*sigmoid ----------------
// VERT=0: lr/rl along w (o =). VERT=1: tb/bt along h (o +=).
// Block: 32-pixel segment of one line; 4 waves (wr=M-half, wc=N-half).
template <int VERT>
__global__ __launch_bounds__(TPB) void k_scan(
    const ushort_t* __restrict__ y, const ushort_t* __restrict__ Gp,
    const float* __restrict__ dwaw, const float* __restrict__ dwab,
    const float* __restrict__ gab, const float* __restrict__ dwbw,
    const float* __restrict__ dwbb, const float* __restrict__ gbb,
    ushort_t* __restrict__ o) {
  __shared__ ushort_t ylds[36 * 256];   // 18KB, row-XOR-swizzled
  __shared__ ushort_t olds[32 * 256];   // 16KB, row-XOR-swizzled
  __shared__ uint4 bst[2048];           // 32KB weight stage (2 kt-slices)
  int tid = threadIdx.x;
  int bid = blockIdx.x;
  int seg = bid % 3, line = (bid / 3) % 96, n = bid / 288;
  int p0 = seg * 32;

  // stage y rows p0-2 .. p0+33 (zero halo)
  for (int u = tid; u < 36 * 32; u += TPB) {
    int r = u >> 5, ks = u & 31;
    int q = p0 - 2 + r;
    uint4 v = make_uint4(0, 0, 0, 0);
    if (q >= 0 && q < 96) {
      long pix = VERT ? ((long)(n * 96 + q) * 96 + line)
                      : ((long)(n * 96 + line) * 96 + q);
      v = *(const uint4*)(y + pix * 256 + ks * 8);
    }
    *(uint4*)((char*)ylds + r * 512 + ((ks * 16) ^ ((r & 7) << 4))) = v;
  }
  __syncthreads();

  int l = tid & 63, w = tid >> 6;
  int wr = w >> 1, wc = w & 1;
  int llo = l & 15, lhi = l >> 4;

  // A fragments (shared by both directions)
  short8x af[8];
  int arow = 2 + wr * 16 + llo;
#pragma unroll
  for (int kt = 0; kt < 8; ++kt)
    af[kt] = *(const short8x*)((char*)ylds + arow * 512 +
                               ((kt * 64 + lhi * 16) ^ ((arow & 7) << 4)));

  float part[8][4];
  for (int diri = 0; diri < 2; ++diri) {
    const uint4* gp4 = (const uint4*)(Gp + (long)(VERT * 2 + diri) * 65536);
    f32x4 acc[8];
#pragma unroll
    for (int nt = 0; nt < 8; ++nt) acc[nt] = (f32x4){0.f, 0.f, 0.f, 0.f};

    for (int s = 0; s < 4; ++s) {
      __syncthreads();
      const uint4* src = gp4 + s * 2048;
      for (int u = tid; u < 2048; u += TPB) bst[u] = src[u];
      __syncthreads();
#pragma unroll
      for (int h2 = 0; h2 < 2; ++h2) {
        short8x a = af[s * 2 + h2];
#pragma unroll
        for (int nt = 0; nt < 8; ++nt) {
          short8x b = *(const short8x*)&bst[(h2 * 16 + wc * 8 + nt) * 64 + l];
          acc[nt] = __builtin_amdgcn_mfma_f32_16x16x32_bf16(a, b, acc[nt], 0, 0, 0);
        }
      }
    }

    // epilogue: conv(5-tap, reversed for dir b) * sigmoid(gate)
    const float* dwv = diri ? dwbw : dwaw;
    const float* dbv = diri ? dwbb : dwab;
    const float* gbv = diri ? gbb : gab;
#pragma unroll
    for (int nt = 0; nt < 8; ++nt) {
      int c = wc * 128 + nt * 16 + llo;
      float wt[5];
#pragma unroll
      for (int t = 0; t < 5; ++t)
        wt[t] = diri ? dwv[(4 - t) * 256 + c] : dwv[t * 256 + c];
      float cbv = dbv[c], gbvv = gbv[c];
#pragma unroll
      for (int r = 0; r < 4; ++r) {
        int p = wr * 16 + lhi * 4 + r;
        float conv = cbv;
#pragma unroll
        for (int t = 0; t < 5; ++t) {
          int ry = p + t;
          float yv = bf2f(*(const ushort_t*)((char*)ylds + ry * 512 +
                                             ((c * 2) ^ ((ry & 7) << 4))));
          conv = fmaf(yv, wt[t], conv);
        }
        float val = conv * sigf(acc[nt][r] + gbvv);
        if (diri == 0) {
          part[nt][r] = val;
        } else {
          float tot = part[nt][r] + val;
          *(ushort_t*)((char*)olds + p * 512 + ((c * 2) ^ ((p & 7) << 4))) = f2bf(tot);
        }
      }
    }
  }
  __syncthreads();

  for (int u = tid; u < 32 * 32; u += TPB) {
    int p = u >> 5, ks = u & 31;
    uint4 v = *(const uint4*)((char*)olds + p * 512 + ((ks * 16) ^ ((p & 7) << 4)));
    long pix = VERT ? ((long)(n * 96 + p0 + p) * 96 + line)
                    : ((long)(n * 96 + line) * 96 + p0 + p);
    ushort_t* dst = o + pix * 256 + ks * 8;
    if (VERT) {
      uint4 old = *(uint4*)dst;
      ushort_t* a8 = (ushort_t*)&v;
      ushort_t* b8 = (ushort_t*)&old;
#pragma unroll
      for (int j = 0; j < 8; ++j) a8[j] = f2bf(bf2f(a8[j]) + bf2f(b8[j]));
      *(uint4*)dst = v;
    } else {
      *(uint4*)dst = v;
    }
  }
}

// ---------------- fuse GEMM (MFMA) + residual: out(NCHW) = x + o@Ft + b ----------------
__global__ __launch_bounds__(TPB) void k_fuse(
    const ushort_t* __restrict__ o, const ushort_t* __restrict__ Ftp,
    const float* __restrict__ fuseb, const float* __restrict__ x,
    float* __restrict__ out) {
  __shared__ ushort_t alds[32 * 256];      // 16KB swizzled
  __shared__ __align__(16) char sbuf[32768];  // bst (uint4) then olds (f32)
  uint4* bst = (uint4*)sbuf;
  float* olds = (float*)sbuf;
  int tid = threadIdx.x;
  int pix0 = blockIdx.x * 32;
  int n = pix0 / HWSZ;
  int hw0 = pix0 % HWSZ;

  for (int u = tid; u < 32 * 32; u += TPB) {
    int r = u >> 5, ks = u & 31;
    uint4 v = *(const uint4*)(o + (long)(pix0 + r) * 256 + ks * 8);
    *(uint4*)((char*)alds + r * 512 + ((ks * 16) ^ ((r & 7) << 4))) = v;
  }
  __syncthreads();

  int l = tid & 63, w = tid >> 6;
  int wr = w >> 1, wc = w & 1;
  int llo = l & 15, lhi = l >> 4;

  short8x af[8];
  int arow = wr * 16 + llo;
#pragma unroll
  for (int kt = 0; kt < 8; ++kt)
    af[kt] = *(const short8x*)((char*)alds + arow * 512 +
                               ((kt * 64 + lhi * 16) ^ ((arow & 7) << 4)));

  f32x4 acc[8];
#pragma unroll
  for (int nt = 0; nt < 8; ++nt) acc[nt] = (f32x4){0.f, 0.f, 0.f, 0.f};

  const uint4* fp4 = (const uint4*)Ftp;
  for (int s = 0; s < 4; ++s) {
    __syncthreads();
    const uint4* src = fp4 + s * 2048;
    for (int u = tid; u < 2048; u += TPB) bst[u] = src[u];
    __syncthreads();
#pragma unroll
    for (int h2 = 0; h2 < 2; ++h2) {
      short8x a = af[s * 2 + h2];
#pragma unroll
      for (int nt = 0; nt < 8; ++nt) {
        short8x b = *(const short8x*)&bst[(h2 * 16 + wc * 8 + nt) * 64 + l];
        acc[nt] = __builtin_amdgcn_mfma_f32_16x16x32_bf16(a, b, acc[nt], 0, 0, 0);
      }
    }
  }
  __syncthreads();  // bst dead -> olds
#pragma unroll
  for (int nt = 0; nt < 8; ++nt) {
    int c = wc * 128 + nt * 16 + llo;
    float fb = fuseb[c];
#pragma unroll
    for (int r = 0; r < 4; ++r) {
      int p = wr * 16 + lhi * 4 + r;
      *(float*)((char*)olds + swz32(p, c)) = acc[nt][r] + fb;
    }
  }
  __syncthreads();
  for (int i = tid; i < 8192; i += TPB) {
    int c = i >> 5, p = i & 31;
    long addr = (long)(n * 256 + c) * HWSZ + hw0 + p;
    out[addr] = x[addr] + *(const float*)((char*)olds + swz32(p, c));
  }
}

// ---------------- ln2 + ff1 + GLU + ff2 + residual (MFMA, out +=) ----------------
__global__ __launch_bounds__(TPB) void k_ff(
    const float* __restrict__ xres, const float* __restrict__ mean2,
    const float* __restrict__ rstd2, const float* __restrict__ ln2w,
    const float* __restrict__ ln2b, const ushort_t* __restrict__ W1p,
    const float* __restrict__ ff1b, const ushort_t* __restrict__ W2p,
    const float* __restrict__ ff2b, float* __restrict__ out) {
  __shared__ ushort_t hA[32 * 256];   // 16KB swizzled
  __shared__ ushort_t uA[32 * 128];   // 8KB swizzled (row stride 256B)
  __shared__ __align__(16) char sbuf[32768];
  uint4* bst = (uint4*)sbuf;
  float* olds = (float*)sbuf;
  int tid = threadIdx.x;
  int pix0 = blockIdx.x * 32;
  int n = pix0 / HWSZ;
  int hw0 = pix0 % HWSZ;

  for (int i = tid; i < 8192; i += TPB) {
    int c = i >> 5, p = i & 31;
    int nc = n * 256 + c;
    float v = xres[(long)nc * HWSZ + hw0 + p];
    float hv = (v - mean2[nc]) * rstd2[nc] * ln2w[c] + ln2b[c];
    *(ushort_t*)((char*)hA + p * 512 + ((c * 2) ^ ((p & 7) << 4))) = f2bf(hv);
  }
  __syncthreads();

  int l = tid & 63, w = tid >> 6;
  int wr = w >> 1, wc = w & 1;
  int llo = l & 15, lhi = l >> 4;

  short8x haf[8];
  int arow = wr * 16 + llo;
#pragma unroll
  for (int kt = 0; kt < 8; ++kt)
    haf[kt] = *(const short8x*)((char*)hA + arow * 512 +
                                ((kt * 64 + lhi * 16) ^ ((arow & 7) << 4)));

  const uint4* W1p4 = (const uint4*)W1p;
  const uint4* W2p4 = (const uint4*)W2p;

  f32x4 zacc[8];
#pragma unroll
  for (int nt = 0; nt < 8; ++nt) zacc[nt] = (f32x4){0.f, 0.f, 0.f, 0.f};

  for (int jc = 0; jc < 4; ++jc) {
    f32x4 tacc[8];
#pragma unroll
    for (int nt = 0; nt < 8; ++nt) tacc[nt] = (f32x4){0.f, 0.f, 0.f, 0.f};

    // GEMM1 chunk: h @ W1p[:, jc-chunk] (K=256)
    for (int s = 0; s < 4; ++s) {
      __syncthreads();
      for (int u = tid; u < 2048; u += TPB) {
        int half = u >> 10, r = u & 1023;
        bst[u] = W1p4[(long)((s * 2 + half) * 64 + jc * 16) * 64 + r];
      }
      __syncthreads();
#pragma unroll
      for (int h2 = 0; h2 < 2; ++h2) {
        short8x a = haf[s * 2 + h2];
#pragma unroll
        for (int nt = 0; nt < 8; ++nt) {
          short8x b = *(const short8x*)&bst[(h2 * 16 + wc * 8 + nt) * 64 + l];
          tacc[nt] = __builtin_amdgcn_mfma_f32_16x16x32_bf16(a, b, tacc[nt], 0, 0, 0);
        }
      }
    }

    // GLU in-register: u = (a+ba)*sig(g+bg); write uA
#pragma unroll
    for (int nt = 0; nt < 4; ++nt) {
      int ca = jc * 128 + wc * 64 + nt * 16 + llo;
      float ba = ff1b[ca], bg = ff1b[512 + ca];
#pragma unroll
      for (int r = 0; r < 4; ++r) {
        float av = tacc[nt][r] + ba;
        float gv = tacc[nt + 4][r] + bg;
        float uv = av * sigf(gv);
        int p = wr * 16 + lhi * 4 + r;
        int cu = wc * 64 + nt * 16 + llo;
        *(ushort_t*)((char*)uA + p * 256 + ((cu * 2) ^ ((p & 7) << 4))) = f2bf(uv);
      }
    }
    __syncthreads();

    // GEMM2 partial: zacc += u @ W2p[jc-chunk] (K=128)
    for (int s2 = 0; s2 < 2; ++s2) {
      __syncthreads();
      for (int u = tid; u < 2048; u += TPB)
        bst[u] = W2p4[(long)(jc * 4 + s2 * 2) * 1024 + u];
      __syncthreads();
#pragma unroll
      for (int h2 = 0; h2 < 2; ++h2) {
        int kt2 = s2 * 2 + h2;
        short8x a2 = *(const short8x*)((char*)uA + arow * 256 +
                                       ((kt2 * 64 + lhi * 16) ^ ((arow & 7) << 4)));
#pragma unroll
        for (int nt = 0; nt < 8; ++nt) {
          short8x b = *(const short8x*)&bst[(h2 * 16 + wc * 8 + nt) * 64 + l];
          zacc[nt] = __builtin_amdgcn_mfma_f32_16x16x32_bf16(a2, b, zacc[nt], 0, 0, 0);
        }
      }
    }
  }

  __syncthreads();  // bst dead -> olds
#pragma unroll
  for (int nt = 0; nt < 8; ++nt) {
    int c = wc * 128 + nt * 16 + llo;
    float fb = ff2b[c];
#pragma unroll
    for (int r = 0; r < 4; ++r) {
      int p = wr * 16 + lhi * 4 + r;
      *(float*)((char*)olds + swz32(p, c)) = zacc[nt][r] + fb;
    }
  }
  __syncthreads();
  for (int i = tid; i < 8192; i += TPB) {
    int c = i >> 5, p = i & 31;
    long addr = (long)(n * 256 + c) * HWSZ + hw0 + p;
    out[addr] += *(const float*)((char*)olds + swz32(p, c));
  }
}

extern "C" void kernel_launch(void* const* d_in, const int* in_sizes, int n_in,
                              void* d_out, int out_size, void* d_ws, size_t ws_size,
                              hipStream_t stream) {
  (void)in_sizes; (void)n_in; (void)out_size; (void)ws_size;
  const float* x     = (const float*)d_in[0];
  const float* ln1w  = (const float*)d_in[1];
  const float* ln1b  = (const float*)d_in[2];
  const float* dww   = (const float*)d_in[3];
  const float* dwb   = (const float*)d_in[4];
  const float* lr_w  = (const float*)d_in[5];
  const float* lr_b  = (const float*)d_in[6];
  const float* lr_gw = (const float*)d_in[7];
  const float* lr_gb = (const float*)d_in[8];
  const float* rl_w  = (const float*)d_in[9];
  const float* rl_b  = (const float*)d_in[10];
  const float* rl_gw = (const float*)d_in[11];
  const float* rl_gb = (const float*)d_in[12];
  const float* tb_w  = (const float*)d_in[13];
  const float* tb_b  = (const float*)d_in[14];
  const float* tb_gw = (const float*)d_in[15];
  const float* tb_gb = (const float*)d_in[16];
  const float* bt_w  = (const float*)d_in[17];
  const float* bt_b  = (const float*)d_in[18];
  const float* bt_gw = (const float*)d_in[19];
  const float* bt_gb = (const float*)d_in[20];
  const float* fusew = (const float*)d_in[21];
  const float* fuseb = (const float*)d_in[22];
  const float* ln2w  = (const float*)d_in[23];
  const float* ln2b  = (const float*)d_in[24];
  const float* ff1w  = (const float*)d_in[25];
  const float* ff1b  = (const float*)d_in[26];
  const float* ff2w  = (const float*)d_in[27];
  const float* ff2b  = (const float*)d_in[28];

  float* out = (float*)d_out;
  ushort_t* y = (ushort_t*)d_ws;                  // 18874368 bf16
  ushort_t* o = y + 18874368;                     // 18874368 bf16
  float* mean1 = (float*)(o + 18874368);
  float* rstd1 = mean1 + 2048;
  float* mean2 = rstd1 + 2048;
  float* rstd2 = mean2 + 2048;
  ushort_t* Gp  = (ushort_t*)(rstd2 + 2048);      // 262144
  ushort_t* Ftp = Gp + 262144;                    // 65536
  ushort_t* W1p = Ftp + 65536;                    // 262144
  ushort_t* W2p = W1p + 262144;                   // 131072

  k_pack<<<2816, TPB, 0, stream>>>(lr_gw, rl_gw, tb_gw, bt_gw, fusew, ff1w, ff2w,
                                   Gp, Ftp, W1p, W2p);
  k_stats<<<2048, TPB, 0, stream>>>(x, mean1, rstd1);
  k_lndw<<<6144, TPB, 0, stream>>>(x, mean1, rstd1, ln1w, ln1b, dww, dwb, y);
  k_scan<0><<<2304, TPB, 0, stream>>>(y, Gp, lr_w, lr_b, lr_gb, rl_w, rl_b, rl_gb, o);
  k_scan<1><<<2304, TPB, 0, stream>>>(y, Gp, tb_w, tb_b, tb_gb, bt_w, bt_b, bt_gb, o);
  k_fuse<<<2304, TPB, 0, stream>>>(o, Ftp, fuseb, x, out);
  k_stats<<<2048, TPB, 0, stream>>>(out, mean2, rstd2);
  k_ff<<<2304, TPB, 0, stream>>>(out, mean2, rstd2, ln2w, ln2b, W1p, ff1b,
                                 W2p, ff2b, out);
}